// Round 13
// baseline (828.175 us; speedup 1.0000x reference)
//
#include <hip/hip_runtime.h>
#include <hip/hip_bf16.h>
#include <stdint.h>

#define M_TOT 8192
#define DIN   1024
#define DEXP  1024
#define NEXP  8

#define BM 256
#define BN 128
#define BK 32
#define NT 128            // 4 expert-pairs * 32 K-tiles
#define KPP 32            // K-tiles per pair
#define SLOT_E 16384      // elems per slot: A 8192 + B0 4096 + B1 4096 (32 KiB)
#define EXPSZ (DEXP * DIN)

typedef __attribute__((ext_vector_type(8))) short bf16x8;
typedef __attribute__((ext_vector_type(16))) float f32x16;
typedef __attribute__((ext_vector_type(8))) unsigned short us8;
typedef _Float16 __attribute__((ext_vector_type(2))) f16x2;

typedef __attribute__((address_space(1))) void* as1vp;
typedef __attribute__((address_space(3))) void* as3vp;

__device__ __forceinline__ unsigned short f2bf(float f) {
    union { float f; unsigned u; } v; v.f = f;
    return (unsigned short)((v.u + 0x7fffu + ((v.u >> 16) & 1u)) >> 16);
}

__device__ __forceinline__ void gl_lds16(const unsigned short* g, unsigned short* l) {
    __builtin_amdgcn_global_load_lds((as1vp)g, (as3vp)l, 16, 0, 0);
}

#define MFMA32(va, vb, vc) __builtin_amdgcn_mfma_f32_32x32x16_bf16(va, vb, vc, 0, 0, 0)

// ------- We (n, din, dexp) fp32 -> Wt (n, dexp, din) bf16, tiled transpose -------
__global__ __launch_bounds__(256) void cvt_w_k(const float* __restrict__ We,
                                               unsigned short* __restrict__ Wt) {
    __shared__ float tile[64][65];
    int n  = blockIdx.z;
    int k0 = blockIdx.y * 64;
    int j0 = blockIdx.x * 64;
    int t  = threadIdx.x;
    int tr = t >> 6, tc = t & 63;
    const float* src = We + (size_t)n * DIN * DEXP;
    #pragma unroll
    for (int rr = 0; rr < 16; ++rr) {
        int r = rr * 4 + tr;
        tile[r][tc] = src[(size_t)(k0 + r) * DEXP + j0 + tc];
    }
    __syncthreads();
    unsigned short* dst = Wt + (size_t)n * DEXP * DIN;
    #pragma unroll
    for (int rr = 0; rr < 16; ++rr) {
        int r = rr * 4 + tr;
        dst[(size_t)(j0 + r) * DIN + k0 + tc] = f2bf(tile[tc][r]);
    }
}

// ------- fused: gate = softmax(x @ Wg + bg) AND Xb = bf16(x) -------
__global__ __launch_bounds__(256) void gatex_k(const float* __restrict__ x,
                                               const float* __restrict__ Wg,
                                               const float* __restrict__ bg,
                                               float* __restrict__ gate,
                                               unsigned short* __restrict__ Xb) {
    __shared__ float wgt[NEXP][DIN];
    int t = threadIdx.x;
    for (int idx = t; idx < DIN * NEXP; idx += 256)
        wgt[idx & 7][idx >> 3] = Wg[idx];
    __syncthreads();
    int wid = t >> 6, lane = t & 63;
    for (int m = blockIdx.x * 4 + wid; m < M_TOT; m += gridDim.x * 4) {
        const float* xr = x + (size_t)m * DIN;
        unsigned short* xb = Xb + (size_t)m * DIN;
        #pragma unroll
        for (int p = 0; p < 2; ++p) {
            int d = p * 512 + lane * 8;
            float4 v0 = *(const float4*)(xr + d);
            float4 v1 = *(const float4*)(xr + d + 4);
            us8 o;
            o[0] = f2bf(v0.x); o[1] = f2bf(v0.y); o[2] = f2bf(v0.z); o[3] = f2bf(v0.w);
            o[4] = f2bf(v1.x); o[5] = f2bf(v1.y); o[6] = f2bf(v1.z); o[7] = f2bf(v1.w);
            *(us8*)(xb + d) = o;
        }
        float acc[NEXP];
        #pragma unroll
        for (int n = 0; n < NEXP; ++n) acc[n] = 0.f;
        for (int i = 0; i < DIN / 64; ++i) {
            int d = i * 64 + lane;
            float xv = xr[d];
            #pragma unroll
            for (int n = 0; n < NEXP; ++n) acc[n] = fmaf(xv, wgt[n][d], acc[n]);
        }
        #pragma unroll
        for (int n = 0; n < NEXP; ++n) {
            #pragma unroll
            for (int off = 32; off; off >>= 1) acc[n] += __shfl_xor(acc[n], off);
            acc[n] += bg[n];
        }
        float mx = acc[0];
        #pragma unroll
        for (int n = 1; n < NEXP; ++n) mx = fmaxf(mx, acc[n]);
        float s = 0.f, e[NEXP];
        #pragma unroll
        for (int n = 0; n < NEXP; ++n) { e[n] = __expf(acc[n] - mx); s += e[n]; }
        float inv = 1.f / s;
        if (lane < NEXP) gate[(size_t)m * NEXP + lane] = e[lane] * inv;
    }
}

// ---- fused MoE GEMM: fat-wave (128x64x2e), 1 wave/SIMD, counted-lgkm pipeline ----
__global__ __launch_bounds__(256, 1) void moe_k(const unsigned short* __restrict__ Xb,
                                                const unsigned short* __restrict__ Wt,
                                                const float* __restrict__ gate,
                                                const float* __restrict__ be,
                                                float* __restrict__ out) {
    __shared__ __align__(16) unsigned short lds[4 * SLOT_E];   // 128 KiB
    __shared__ float gateL[BM * NEXP];                          // 8 KiB
    __shared__ float biasL[NEXP * BN];                          // 4 KiB

    const int t    = threadIdx.x;
    const int lane = t & 63;
    const int wv   = t >> 6;            // 0..3
    const int wm   = wv >> 1;           // 0..1 (M, 128 rows each)
    const int wn   = wv & 1;            // 0..1 (N, 64 cols each)
    const int l31  = lane & 31;
    const int lhi  = lane >> 5;         // 0/1

    // bijective XCD swizzle (grid 256)
    const int b    = blockIdx.x;
    const int lg   = (b & 7) * 32 + (b >> 3);
    const int brow = (lg >> 3) * BM;    // 32 M-tiles
    const int bcol = (lg & 7) * BN;     // 8 N-tiles

    // staging: thread t -> row t>>2 (64B rows), phys chunk t&3; inverse swizzle source
    const int sA = (t >> 2) * DIN + ((((t & 3) - (t >> 3)) & 3) * 8);
    const unsigned short* gA = Xb + (size_t)brow * DIN;
    const unsigned short* gB = Wt + (size_t)bcol * DIN;

    // fragment read offsets: phys chunk = (c_log + (row>>1)) & 3, c_log = ks*2 + lhi
    const int kc0   = ((lhi + (l31 >> 1)) & 3) * 8;
    const int aOff0 = (wm * 128 + l31) * 32 + kc0;          // + mf*1024 ; ks1: ^16
    const int bOff0 = 8192 + (wn * 64 + l31) * 32 + kc0;    // + nf*1024 ; B1: +4096

#define STAGE_A(sl_, k0_) do { \
    const unsigned short* g_ = gA + (k0_) + sA; \
    unsigned short* d_ = (unsigned short*)lds + (sl_) * SLOT_E + t * 8; \
    gl_lds16(g_, d_); gl_lds16(g_ + 64 * DIN, d_ + 2048); \
    gl_lds16(g_ + 128 * DIN, d_ + 4096); gl_lds16(g_ + 192 * DIN, d_ + 6144); } while (0)
#define STAGE_B0(sl_, e_, k0_) do { \
    const unsigned short* g_ = gB + (size_t)(e_) * EXPSZ + (k0_) + sA; \
    unsigned short* d_ = (unsigned short*)lds + (sl_) * SLOT_E + 8192 + t * 8; \
    gl_lds16(g_, d_); gl_lds16(g_ + 64 * DIN, d_ + 2048); } while (0)
#define STAGE_B1(sl_, e_, k0_) do { \
    const unsigned short* g_ = gB + (size_t)(e_) * EXPSZ + (k0_) + sA; \
    unsigned short* d_ = (unsigned short*)lds + (sl_) * SLOT_E + 12288 + t * 8; \
    gl_lds16(g_, d_); gl_lds16(g_ + 64 * DIN, d_ + 2048); } while (0)

#define RD_B0(L_) do { \
    b0[0][0] = *(const bf16x8*)((L_) + bOff0); \
    b0[0][1] = *(const bf16x8*)((L_) + (bOff0 ^ 16)); \
    b0[1][0] = *(const bf16x8*)((L_) + bOff0 + 1024); \
    b0[1][1] = *(const bf16x8*)((L_) + (bOff0 ^ 16) + 1024); } while (0)
#define RD_A(L_) do { \
    _Pragma("unroll") \
    for (int mf_ = 0; mf_ < 4; ++mf_) { \
        a[mf_][0] = *(const bf16x8*)((L_) + aOff0 + mf_ * 1024); \
        a[mf_][1] = *(const bf16x8*)((L_) + (aOff0 ^ 16) + mf_ * 1024); \
    } } while (0)
#define RD_B1(L_) do { \
    b1[0][0] = *(const bf16x8*)((L_) + bOff0 + 4096); \
    b1[0][1] = *(const bf16x8*)((L_) + (bOff0 ^ 16) + 4096); \
    b1[1][0] = *(const bf16x8*)((L_) + bOff0 + 5120); \
    b1[1][1] = *(const bf16x8*)((L_) + (bOff0 ^ 16) + 5120); } while (0)

    f32x16 acc_e0[4][2] = {};
    f32x16 acc_e1[4][2] = {};
    f16x2  acc_p[4][2][8];              // packed gated running sum (64 VGPR)
    bf16x8 a[4][2], b0[2][2], b1[2][2];

    #pragma unroll
    for (int mf = 0; mf < 4; ++mf)
        #pragma unroll
        for (int nf = 0; nf < 2; ++nf)
            #pragma unroll
            for (int p = 0; p < 8; ++p)
                acc_p[mf][nf][p] = (f16x2){(_Float16)0.f, (_Float16)0.f};

    // ---- prologue: gate+bias -> LDS; stage tiles 0,1,2 ----
    {
        const float* gp = gate + (size_t)brow * NEXP;      // 2048 floats
        ((float4*)gateL)[t]       = ((const float4*)gp)[t];
        ((float4*)gateL)[t + 256] = ((const float4*)gp)[t + 256];
        ((float4*)biasL)[t] =
            *(const float4*)(be + (size_t)(t >> 5) * DEXP + bcol + (t & 31) * 4);
    }
    STAGE_A(0, 0);  STAGE_B0(0, 0, 0);  STAGE_B1(0, 1, 0);
    STAGE_A(1, 32); STAGE_B0(1, 0, 32); STAGE_B1(1, 1, 32);
    STAGE_A(2, 64); STAGE_B0(2, 0, 64); STAGE_B1(2, 1, 64);
    asm volatile("s_waitcnt vmcnt(16)" ::: "memory");   // tile 0 landed; 1,2 in flight
    asm volatile("s_waitcnt lgkmcnt(0)" ::: "memory");  // gate/bias committed
    __builtin_amdgcn_s_barrier();
    // pre-issue tile-0 fragment reads (age order: b0 < a < b1; 16 outstanding)
    RD_B0(lds);
    __builtin_amdgcn_sched_barrier(0);
    RD_A(lds);
    __builtin_amdgcn_sched_barrier(0);
    RD_B1(lds);
    __builtin_amdgcn_sched_barrier(0);

    for (int T = 0; T < NT; ++T) {
        const unsigned short* L1 = lds + ((T + 1) & 3) * SLOT_E;

        // entry: outstanding ds = b0(4), a(8), b1(4) = 16
        asm volatile("s_waitcnt lgkmcnt(4)" ::: "memory");   // b0,a ready; b1 in flight
        __builtin_amdgcn_sched_barrier(0);
        __builtin_amdgcn_s_setprio(1);
        #pragma unroll
        for (int mf = 0; mf < 4; ++mf)
            #pragma unroll
            for (int nf = 0; nf < 2; ++nf) {
                acc_e0[mf][nf] = MFMA32(a[mf][0], b0[nf][0], acc_e0[mf][nf]);
                acc_e0[mf][nf] = MFMA32(a[mf][1], b0[nf][1], acc_e0[mf][nf]);
            }
        __builtin_amdgcn_s_setprio(0);
        __builtin_amdgcn_sched_barrier(0);

        // issue b0(T+1) into freed regs; its LDS service overlaps MFMA e1
        if (T < NT - 1) {
            RD_B0(L1);
            asm volatile("s_waitcnt lgkmcnt(4)" ::: "memory");  // b1(T) ready
        } else {
            asm volatile("s_waitcnt lgkmcnt(0)" ::: "memory");
        }
        __builtin_amdgcn_sched_barrier(0);
        __builtin_amdgcn_s_setprio(1);
        #pragma unroll
        for (int mf = 0; mf < 4; ++mf)
            #pragma unroll
            for (int nf = 0; nf < 2; ++nf) {
                acc_e1[mf][nf] = MFMA32(a[mf][0], b1[nf][0], acc_e1[mf][nf]);
                acc_e1[mf][nf] = MFMA32(a[mf][1], b1[nf][1], acc_e1[mf][nf]);
            }
        __builtin_amdgcn_s_setprio(0);
        __builtin_amdgcn_sched_barrier(0);

        // issue a(T+1), b1(T+1)
        if (T < NT - 1) {
            RD_A(L1);
            __builtin_amdgcn_sched_barrier(0);
            RD_B1(L1);
            __builtin_amdgcn_sched_barrier(0);
        }

        // stage tile T+3
        if (T < NT - 3) {
            const int s3 = (T + 3) & 3;
            const int e3 = ((T + 3) >> 5) * 2;
            const int k3 = ((T + 3) & (KPP - 1)) * BK;
            STAGE_A(s3, k3); STAGE_B0(s3, e3, k3); STAGE_B1(s3, e3 + 1, k3);
        }

        // ---- fused pair epilogue (every 32 iters; LDS broadcast + regs only) ----
        if ((T & (KPP - 1)) == (KPP - 1)) {
            const int e0 = (T >> 5) * 2, e1 = e0 + 1;
            float bi0[2], bi1[2];
            #pragma unroll
            for (int nf = 0; nf < 2; ++nf) {
                bi0[nf] = biasL[e0 * BN + wn * 64 + nf * 32 + l31];
                bi1[nf] = biasL[e1 * BN + wn * 64 + nf * 32 + l31];
            }
            #pragma unroll
            for (int mf = 0; mf < 4; ++mf) {
                #pragma unroll
                for (int p = 0; p < 8; ++p) {
                    const int r0 = 2 * p, r1 = 2 * p + 1;
                    const int rl0 = wm * 128 + mf * 32 + (r0 & 3) + 8 * (r0 >> 2) + 4 * lhi;
                    const int rl1 = wm * 128 + mf * 32 + (r1 & 3) + 8 * (r1 >> 2) + 4 * lhi;
                    const float g00 = gateL[rl0 * NEXP + e0];
                    const float g01 = gateL[rl0 * NEXP + e1];
                    const float g10 = gateL[rl1 * NEXP + e0];
                    const float g11 = gateL[rl1 * NEXP + e1];
                    #pragma unroll
                    for (int nf = 0; nf < 2; ++nf) {
                        f16x2 o = acc_p[mf][nf][p];
                        float v0 = (float)o[0]
                            + g00 * fmaxf(acc_e0[mf][nf][r0] + bi0[nf], 0.f)
                            + g01 * fmaxf(acc_e1[mf][nf][r0] + bi1[nf], 0.f);
                        float v1 = (float)o[1]
                            + g10 * fmaxf(acc_e0[mf][nf][r1] + bi0[nf], 0.f)
                            + g11 * fmaxf(acc_e1[mf][nf][r1] + bi1[nf], 0.f);
                        acc_p[mf][nf][p] = (f16x2){(_Float16)v0, (_Float16)v1};
                    }
                }
            }
            #pragma unroll
            for (int mf = 0; mf < 4; ++mf)
                #pragma unroll
                for (int nf = 0; nf < 2; ++nf) {
                    acc_e0[mf][nf] = (f32x16){};
                    acc_e1[mf][nf] = (f32x16){};
                }
        }

        // counted vmcnt: 8 loads/tile; T+1 landed, T+2/T+3 in flight
        if (T < NT - 3) { asm volatile("s_waitcnt vmcnt(16)" ::: "memory"); }
        else            { asm volatile("s_waitcnt vmcnt(0)"  ::: "memory"); }
        __builtin_amdgcn_s_barrier();
    }

    // final store (once): unpack f16 running sums
    #pragma unroll
    for (int mf = 0; mf < 4; ++mf) {
        #pragma unroll
        for (int p = 0; p < 8; ++p) {
            const int r0 = 2 * p, r1 = 2 * p + 1;
            const int rl0 = wm * 128 + mf * 32 + (r0 & 3) + 8 * (r0 >> 2) + 4 * lhi;
            const int rl1 = wm * 128 + mf * 32 + (r1 & 3) + 8 * (r1 >> 2) + 4 * lhi;
            float* op0 = out + (size_t)(brow + rl0) * DEXP + bcol + wn * 64 + l31;
            float* op1 = out + (size_t)(brow + rl1) * DEXP + bcol + wn * 64 + l31;
            #pragma unroll
            for (int nf = 0; nf < 2; ++nf) {
                op0[nf * 32] = (float)acc_p[mf][nf][p][0];
                op1[nf * 32] = (float)acc_p[mf][nf][p][1];
            }
        }
    }
#undef STAGE_A
#undef STAGE_B0
#undef STAGE_B1
#undef RD_A
#undef RD_B0
#undef RD_B1
}

extern "C" void kernel_launch(void* const* d_in, const int* in_sizes, int n_in,
                              void* d_out, int out_size, void* d_ws, size_t ws_size,
                              hipStream_t stream) {
    const float* x  = (const float*)d_in[0];
    const float* We = (const float*)d_in[1];
    const float* be = (const float*)d_in[2];
    const float* Wg = (const float*)d_in[3];
    const float* bg = (const float*)d_in[4];
    float* out = (float*)d_out;

    unsigned short* Xb = (unsigned short*)d_ws;                    // 16 MiB bf16 x
    unsigned short* Wt = Xb + (size_t)M_TOT * DIN;                 // 16 MiB bf16 We^T
    float* gate = (float*)(Wt + (size_t)NEXP * DEXP * DIN);        // 256 KiB fp32 gate

    hipLaunchKernelGGL(cvt_w_k, dim3(16, 16, 8), dim3(256), 0, stream, We, Wt);
    hipLaunchKernelGGL(gatex_k, dim3(512), dim3(256), 0, stream, x, Wg, bg, gate, Xb);
    hipLaunchKernelGGL(moe_k, dim3((M_TOT / BM) * (DEXP / BN)), dim3(256), 0, stream,
                       Xb, Wt, gate, be, out);
}

// Round 14
// 159.648 us; speedup vs baseline: 5.1875x; 5.1875x over previous
//
#include <hip/hip_runtime.h>
#include <hip/hip_bf16.h>
#include <stdint.h>

#define M_TOT 8192
#define DIN   1024
#define DEXP  1024
#define NEXP  8

#define BM 256
#define BN 128
#define BK 32
#define NT 128            // 4 expert-pairs * 32 K-tiles
#define KPP 32            // K-tiles per pair
#define SLOT_E 16384      // elems per LDS slot: A 8192 + B0 4096 + B1 4096 (32 KiB)
#define EXPSZ (DEXP * DIN)

typedef __attribute__((ext_vector_type(8))) short bf16x8;
typedef __attribute__((ext_vector_type(16))) float f32x16;
typedef __attribute__((ext_vector_type(8))) unsigned short us8;

typedef __attribute__((address_space(1))) void* as1vp;
typedef __attribute__((address_space(3))) void* as3vp;

__device__ __forceinline__ unsigned short f2bf(float f) {
    union { float f; unsigned u; } v; v.f = f;
    return (unsigned short)((v.u + 0x7fffu + ((v.u >> 16) & 1u)) >> 16);
}

__device__ __forceinline__ void gl_lds16(const unsigned short* g, unsigned short* l) {
    __builtin_amdgcn_global_load_lds((as1vp)g, (as3vp)l, 16, 0, 0);
}

#define MFMA32(va, vb, vc) __builtin_amdgcn_mfma_f32_32x32x16_bf16(va, vb, vc, 0, 0, 0)

// ------- We (n, din, dexp) fp32 -> Wt (n, dexp, din) bf16, tiled transpose -------
__global__ __launch_bounds__(256) void cvt_w_k(const float* __restrict__ We,
                                               unsigned short* __restrict__ Wt) {
    __shared__ float tile[64][65];
    int n  = blockIdx.z;
    int k0 = blockIdx.y * 64;
    int j0 = blockIdx.x * 64;
    int t  = threadIdx.x;
    int tr = t >> 6, tc = t & 63;
    const float* src = We + (size_t)n * DIN * DEXP;
    #pragma unroll
    for (int rr = 0; rr < 16; ++rr) {
        int r = rr * 4 + tr;
        tile[r][tc] = src[(size_t)(k0 + r) * DEXP + j0 + tc];
    }
    __syncthreads();
    unsigned short* dst = Wt + (size_t)n * DEXP * DIN;
    #pragma unroll
    for (int rr = 0; rr < 16; ++rr) {
        int r = rr * 4 + tr;
        dst[(size_t)(j0 + r) * DIN + k0 + tc] = f2bf(tile[tc][r]);
    }
}

// ------- fused: gate = softmax(x @ Wg + bg) AND Xb = bf16(x) -------
__global__ __launch_bounds__(256) void gatex_k(const float* __restrict__ x,
                                               const float* __restrict__ Wg,
                                               const float* __restrict__ bg,
                                               float* __restrict__ gate,
                                               unsigned short* __restrict__ Xb) {
    __shared__ float wgt[NEXP][DIN];
    int t = threadIdx.x;
    for (int idx = t; idx < DIN * NEXP; idx += 256)
        wgt[idx & 7][idx >> 3] = Wg[idx];
    __syncthreads();
    int wid = t >> 6, lane = t & 63;
    for (int m = blockIdx.x * 4 + wid; m < M_TOT; m += gridDim.x * 4) {
        const float* xr = x + (size_t)m * DIN;
        unsigned short* xb = Xb + (size_t)m * DIN;
        #pragma unroll
        for (int p = 0; p < 2; ++p) {
            int d = p * 512 + lane * 8;
            float4 v0 = *(const float4*)(xr + d);
            float4 v1 = *(const float4*)(xr + d + 4);
            us8 o;
            o[0] = f2bf(v0.x); o[1] = f2bf(v0.y); o[2] = f2bf(v0.z); o[3] = f2bf(v0.w);
            o[4] = f2bf(v1.x); o[5] = f2bf(v1.y); o[6] = f2bf(v1.z); o[7] = f2bf(v1.w);
            *(us8*)(xb + d) = o;
        }
        float acc[NEXP];
        #pragma unroll
        for (int n = 0; n < NEXP; ++n) acc[n] = 0.f;
        for (int i = 0; i < DIN / 64; ++i) {
            int d = i * 64 + lane;
            float xv = xr[d];
            #pragma unroll
            for (int n = 0; n < NEXP; ++n) acc[n] = fmaf(xv, wgt[n][d], acc[n]);
        }
        #pragma unroll
        for (int n = 0; n < NEXP; ++n) {
            #pragma unroll
            for (int off = 32; off; off >>= 1) acc[n] += __shfl_xor(acc[n], off);
            acc[n] += bg[n];
        }
        float mx = acc[0];
        #pragma unroll
        for (int n = 1; n < NEXP; ++n) mx = fmaxf(mx, acc[n]);
        float s = 0.f, e[NEXP];
        #pragma unroll
        for (int n = 0; n < NEXP; ++n) { e[n] = __expf(acc[n] - mx); s += e[n]; }
        float inv = 1.f / s;
        if (lane < NEXP) gate[(size_t)m * NEXP + lane] = e[lane] * inv;
    }
}

// ---- fused MoE GEMM: expert-pair, 32x32x16, counted-lgkm overlap, 1 barrier/iter ----
// (round-7 champion configuration, verbatim)
__global__ __launch_bounds__(512, 2) void moe_k(const unsigned short* __restrict__ Xb,
                                                const unsigned short* __restrict__ Wt,
                                                const float* __restrict__ gate,
                                                const float* __restrict__ be,
                                                float* __restrict__ out) {
    // 4 rotating slots: A [256][32] (0..8191), B0 (8192..12287), B1 (12288..16383)
    __shared__ __align__(16) unsigned short lds[4 * SLOT_E];   // 128 KiB
    __shared__ float gateL[BM * NEXP];                          // 8 KiB
    __shared__ float biasL[NEXP * BN];                          // 4 KiB

    const int t    = threadIdx.x;
    const int lane = t & 63;
    const int wv   = t >> 6;
    const int wm   = wv >> 1;           // 0..3 (M)
    const int wn   = wv & 1;            // 0..1 (N)
    const int l31  = lane & 31;
    const int lhi  = lane >> 5;         // 0/1

    // bijective XCD swizzle; per-XCD chunk = 4 M-tiles x 8 N-tiles
    const int b    = blockIdx.x;
    const int lg   = (b & 7) * 32 + (b >> 3);
    const int brow = (lg >> 3) * BM;    // 32 M-tiles
    const int bcol = (lg & 7) * BN;     // 8 N-tiles

    // staging: thread t -> row t>>2 (64B rows), phys chunk t&3; inverse swizzle on source
    const int sA = (t >> 2) * DIN + ((((t & 3) - (t >> 3)) & 3) * 8);
    const unsigned short* gA = Xb + (size_t)brow * DIN;
    const unsigned short* gB = Wt + (size_t)bcol * DIN;

    // fragment read offsets: phys chunk = (c_log + (row>>1)) & 3, c_log = ks*2 + lhi
    const int kc0 = ((lhi + (l31 >> 1)) & 3) * 8;
    const int kc1 = kc0 ^ 16;
    const int aOff0 = (wm * 64 + l31) * 32 + kc0;         // + mf*1024
    const int aOff1 = (wm * 64 + l31) * 32 + kc1;
    const int bOff0 = 8192 + (wn * 64 + l31) * 32 + kc0;  // + nf*1024 ; B1: +4096
    const int bOff1 = 8192 + (wn * 64 + l31) * 32 + kc1;

#define STAGE_A(sl_, k0_) do { \
    const unsigned short* g_ = gA + (k0_) + sA; \
    unsigned short* d_ = (unsigned short*)lds + (sl_) * SLOT_E + t * 8; \
    gl_lds16(g_, d_); gl_lds16(g_ + 128 * DIN, d_ + 4096); } while (0)
#define STAGE_B0(sl_, e_, k0_) do { \
    gl_lds16(gB + (size_t)(e_) * EXPSZ + (k0_) + sA, \
             (unsigned short*)lds + (sl_) * SLOT_E + 8192 + t * 8); } while (0)
#define STAGE_B1(sl_, e_, k0_) do { \
    gl_lds16(gB + (size_t)(e_) * EXPSZ + (k0_) + sA, \
             (unsigned short*)lds + (sl_) * SLOT_E + 12288 + t * 8); } while (0)

#define RD_B0(L_) do { \
    b0[0][0] = *(const bf16x8*)((L_) + bOff0); \
    b0[0][1] = *(const bf16x8*)((L_) + bOff1); \
    b0[1][0] = *(const bf16x8*)((L_) + bOff0 + 1024); \
    b0[1][1] = *(const bf16x8*)((L_) + bOff1 + 1024); } while (0)
#define RD_A(L_) do { \
    a[0][0] = *(const bf16x8*)((L_) + aOff0); \
    a[0][1] = *(const bf16x8*)((L_) + aOff1); \
    a[1][0] = *(const bf16x8*)((L_) + aOff0 + 1024); \
    a[1][1] = *(const bf16x8*)((L_) + aOff1 + 1024); } while (0)
#define RD_B1(L_) do { \
    b1[0][0] = *(const bf16x8*)((L_) + bOff0 + 4096); \
    b1[0][1] = *(const bf16x8*)((L_) + bOff1 + 4096); \
    b1[1][0] = *(const bf16x8*)((L_) + bOff0 + 5120); \
    b1[1][1] = *(const bf16x8*)((L_) + bOff1 + 5120); } while (0)

    f32x16 acc_e0[2][2] = {};
    f32x16 acc_e1[2][2] = {};
    f32x16 acc_o[2][2]  = {};
    bf16x8 a[2][2], b0[2][2], b1[2][2];

    // ---- prologue ----
    {
        const float* gp = gate + (size_t)brow * NEXP;     // 2048 floats
        ((float4*)gateL)[t] = ((const float4*)gp)[t];
        if (t < 256)                                       // 1024 floats
            ((float4*)biasL)[t] =
                *(const float4*)(be + (size_t)(t >> 5) * DEXP + bcol + (t & 31) * 4);
    }
    STAGE_A(0, 0);  STAGE_B0(0, 0, 0);  STAGE_B1(0, 1, 0);
    STAGE_A(1, 32); STAGE_B0(1, 0, 32); STAGE_B1(1, 1, 32);
    STAGE_A(2, 64); STAGE_B0(2, 0, 64); STAGE_B1(2, 1, 64);
    asm volatile("s_waitcnt vmcnt(4)" ::: "memory");    // tiles 0,1 landed; tile 2 in flight
    asm volatile("s_waitcnt lgkmcnt(0)" ::: "memory");  // gate/bias committed
    __builtin_amdgcn_s_barrier();
    // pre-issue tile-0 fragment reads (age order: b0 < a < b1)
    RD_B0(lds); RD_A(lds);
    __builtin_amdgcn_sched_barrier(0);
    RD_B1(lds);
    __builtin_amdgcn_sched_barrier(0);

    for (int T = 0; T < NT; ++T) {
        // entry: outstanding ds = b0(T),a(T),b1(T) = 12
        asm volatile("s_waitcnt lgkmcnt(4)" ::: "memory");   // a,b0 ready; b1 in flight
        __builtin_amdgcn_sched_barrier(0);
        __builtin_amdgcn_s_setprio(1);
        #pragma unroll
        for (int mf = 0; mf < 2; ++mf)
            #pragma unroll
            for (int nf = 0; nf < 2; ++nf) {
                acc_e0[mf][nf] = MFMA32(a[mf][0], b0[nf][0], acc_e0[mf][nf]);
                acc_e0[mf][nf] = MFMA32(a[mf][1], b0[nf][1], acc_e0[mf][nf]);
            }
        __builtin_amdgcn_s_setprio(0);

        // issue b0(T+1) into freed regs; its LDS service overlaps MFMA2
        if (T < NT - 1) {
            const unsigned short* L1 = lds + ((T + 1) & 3) * SLOT_E;
            RD_B0(L1);
            asm volatile("s_waitcnt lgkmcnt(4)" ::: "memory");  // b1(T) ready
        } else {
            asm volatile("s_waitcnt lgkmcnt(0)" ::: "memory");
        }
        __builtin_amdgcn_sched_barrier(0);
        __builtin_amdgcn_s_setprio(1);
        #pragma unroll
        for (int mf = 0; mf < 2; ++mf)
            #pragma unroll
            for (int nf = 0; nf < 2; ++nf) {
                acc_e1[mf][nf] = MFMA32(a[mf][0], b1[nf][0], acc_e1[mf][nf]);
                acc_e1[mf][nf] = MFMA32(a[mf][1], b1[nf][1], acc_e1[mf][nf]);
            }
        __builtin_amdgcn_s_setprio(0);

        // ---- fused pair epilogue (every 32 iters; LDS+regs only) ----
        if ((T & (KPP - 1)) == (KPP - 1)) {
            const int e0 = (T >> 5) * 2, e1 = e0 + 1;
            float bi0[2], bi1[2];
            #pragma unroll
            for (int nf = 0; nf < 2; ++nf) {
                bi0[nf] = biasL[e0 * BN + wn * 64 + nf * 32 + l31];
                bi1[nf] = biasL[e1 * BN + wn * 64 + nf * 32 + l31];
            }
            #pragma unroll
            for (int mf = 0; mf < 2; ++mf) {
                #pragma unroll
                for (int reg = 0; reg < 16; ++reg) {
                    const int rl = wm * 64 + mf * 32 + (reg & 3) + 8 * (reg >> 2) + 4 * lhi;
                    const float g0 = gateL[rl * NEXP + e0];
                    const float g1 = gateL[rl * NEXP + e1];
                    #pragma unroll
                    for (int nf = 0; nf < 2; ++nf) {
                        acc_o[mf][nf][reg] += g0 * fmaxf(acc_e0[mf][nf][reg] + bi0[nf], 0.f)
                                            + g1 * fmaxf(acc_e1[mf][nf][reg] + bi1[nf], 0.f);
                    }
                }
            }
            #pragma unroll
            for (int mf = 0; mf < 2; ++mf)
                #pragma unroll
                for (int nf = 0; nf < 2; ++nf) {
                    acc_e0[mf][nf] = (f32x16){};
                    acc_e1[mf][nf] = (f32x16){};
                }
        }

        // issue a(T+1), b1(T+1) (regs freed by MFMA2)
        if (T < NT - 1) {
            const unsigned short* L1 = lds + ((T + 1) & 3) * SLOT_E;
            RD_A(L1);
            __builtin_amdgcn_sched_barrier(0);
            RD_B1(L1);
            __builtin_amdgcn_sched_barrier(0);
        }

        // stage tile T+3; counted vmcnt retires tile T+2; single barrier
        if (T < NT - 3) {
            const int s3 = (T + 3) & 3;
            const int e3 = ((T + 3) >> 5) * 2;
            const int k3 = ((T + 3) & (KPP - 1)) * BK;
            STAGE_A(s3, k3); STAGE_B0(s3, e3, k3); STAGE_B1(s3, e3 + 1, k3);
            asm volatile("s_waitcnt vmcnt(4)" ::: "memory");
        } else {
            asm volatile("s_waitcnt vmcnt(0)" ::: "memory");
        }
        __builtin_amdgcn_s_barrier();
    }

    // final store (once)
    #pragma unroll
    for (int mf = 0; mf < 2; ++mf) {
        #pragma unroll
        for (int reg = 0; reg < 16; ++reg) {
            const int rl = wm * 64 + mf * 32 + (reg & 3) + 8 * (reg >> 2) + 4 * lhi;
            float* op = out + (size_t)(brow + rl) * DEXP + bcol + wn * 64 + l31;
            #pragma unroll
            for (int nf = 0; nf < 2; ++nf) op[nf * 32] = acc_o[mf][nf][reg];
        }
    }
#undef STAGE_A
#undef STAGE_B0
#undef STAGE_B1
#undef RD_A
#undef RD_B0
#undef RD_B1
}

extern "C" void kernel_launch(void* const* d_in, const int* in_sizes, int n_in,
                              void* d_out, int out_size, void* d_ws, size_t ws_size,
                              hipStream_t stream) {
    const float* x  = (const float*)d_in[0];
    const float* We = (const float*)d_in[1];
    const float* be = (const float*)d_in[2];
    const float* Wg = (const float*)d_in[3];
    const float* bg = (const float*)d_in[4];
    float* out = (float*)d_out;

    unsigned short* Xb = (unsigned short*)d_ws;                    // 16 MiB bf16 x
    unsigned short* Wt = Xb + (size_t)M_TOT * DIN;                 // 16 MiB bf16 We^T
    float* gate = (float*)(Wt + (size_t)NEXP * DEXP * DIN);        // 256 KiB fp32 gate

    hipLaunchKernelGGL(cvt_w_k, dim3(16, 16, 8), dim3(256), 0, stream, We, Wt);
    hipLaunchKernelGGL(gatex_k, dim3(512), dim3(256), 0, stream, x, Wg, bg, gate, Xb);
    hipLaunchKernelGGL(moe_k, dim3((M_TOT / BM) * (DEXP / BN)), dim3(512), 0, stream,
                       Xb, Wt, gate, be, out);
}